// Round 1
// baseline (698.021 us; speedup 1.0000x reference)
//
#include <hip/hip_runtime.h>
#include <hip/hip_bf16.h>

#define NTOK 8192
#define DM 1024
#define DFF 4096
#define NE 8

typedef __attribute__((ext_vector_type(8))) short bf16x8;
typedef __attribute__((ext_vector_type(4))) float f32x4;

__device__ __forceinline__ ushort f2bf(float f) {
  __hip_bfloat16 h = __float2bfloat16(f);
  return *reinterpret_cast<ushort*>(&h);
}

// ---------------- x fp32 -> bf16 ----------------
__global__ void cvt_x_kernel(const float* __restrict__ x, ushort* __restrict__ xb) {
  int i = blockIdx.x * 256 + threadIdx.x;
  float4 v = reinterpret_cast<const float4*>(x)[i];
  ushort4 o;
  o.x = f2bf(v.x); o.y = f2bf(v.y); o.z = f2bf(v.z); o.w = f2bf(v.w);
  reinterpret_cast<ushort4*>(xb)[i] = o;
}

// ---------- W [R][C] fp32 -> Wt [C][R] bf16, per expert (blockIdx.z) ----------
__global__ void transpose_cvt(const float* __restrict__ in, ushort* __restrict__ out,
                              int R, int C) {
  __shared__ float t[64][65];
  const float* inp = in + (size_t)blockIdx.z * R * C;
  ushort* op = out + (size_t)blockIdx.z * R * C;
  int c0 = blockIdx.x * 64, r0 = blockIdx.y * 64;
  int tid = threadIdx.x;
#pragma unroll
  for (int it = 0; it < 4; ++it) {
    int r = it * 16 + (tid >> 4);
    int c = (tid & 15) * 4;
    float4 v = *reinterpret_cast<const float4*>(inp + (size_t)(r0 + r) * C + c0 + c);
    t[r][c] = v.x; t[r][c + 1] = v.y; t[r][c + 2] = v.z; t[r][c + 3] = v.w;
  }
  __syncthreads();
  int c = tid >> 2, rc = (tid & 3) * 16;
  union { ushort us[16]; uint4 q[2]; } u;
#pragma unroll
  for (int i = 0; i < 16; ++i) u.us[i] = f2bf(t[rc + i][c]);
  uint4* dst = reinterpret_cast<uint4*>(op + (size_t)(c0 + c) * R + r0 + rc);
  dst[0] = u.q[0];
  dst[1] = u.q[1];
}

// ---------------- router: logits, top-2, softmax, build expert lists ----------------
__global__ void router_kernel(const float* __restrict__ x, const float* __restrict__ router,
                              int* __restrict__ cnt, int* __restrict__ list,
                              float* __restrict__ wa) {
  __shared__ float rl[DM * NE];  // 32 KB
  int tid = threadIdx.x;
  for (int i = tid; i < DM * NE / 4; i += 256)
    reinterpret_cast<float4*>(rl)[i] = reinterpret_cast<const float4*>(router)[i];
  __syncthreads();
  int wave = tid >> 6, lane = tid & 63;
  int tok0 = blockIdx.x * 32 + wave * 8;
  for (int tI = 0; tI < 8; ++tI) {
    int tok = tok0 + tI;
    float acc[NE];
#pragma unroll
    for (int e2 = 0; e2 < NE; ++e2) acc[e2] = 0.f;
    const float4* xr = reinterpret_cast<const float4*>(x + (size_t)tok * DM);
#pragma unroll
    for (int c = 0; c < 4; ++c) {
      float4 v = xr[lane * 4 + c];
      int d = lane * 16 + c * 4;
      const float* vv = reinterpret_cast<const float*>(&v);
#pragma unroll
      for (int q = 0; q < 4; ++q) {
        float xv = vv[q];
#pragma unroll
        for (int e2 = 0; e2 < NE; ++e2) acc[e2] += xv * rl[(d + q) * NE + e2];
      }
    }
    for (int off = 32; off > 0; off >>= 1) {
#pragma unroll
      for (int e2 = 0; e2 < NE; ++e2) acc[e2] += __shfl_xor(acc[e2], off, 64);
    }
    if (lane == 0) {
      int i0 = 0; float v0 = acc[0];
#pragma unroll
      for (int e2 = 1; e2 < NE; ++e2) { if (acc[e2] > v0) { v0 = acc[e2]; i0 = e2; } }
      int i1 = -1; float v1 = -3.4e38f;
#pragma unroll
      for (int e2 = 0; e2 < NE; ++e2) { if (e2 != i0 && acc[e2] > v1) { v1 = acc[e2]; i1 = e2; } }
      float e1 = expf(v1 - v0);
      float w0 = 1.f / (1.f + e1);
      float w1 = e1 / (1.f + e1);
      int s0 = atomicAdd(&cnt[i0], 1);
      list[i0 * NTOK + s0] = tok * 2;
      wa[tok * 2] = w0;
      int s1 = atomicAdd(&cnt[i1], 1);
      list[i1 * NTOK + s1] = tok * 2 + 1;
      wa[tok * 2 + 1] = w1;
    }
  }
}

// ---------------- async global->LDS helper ----------------
__device__ __forceinline__ void gl_lds16(const void* g, void* s) {
  __builtin_amdgcn_global_load_lds(
      (const __attribute__((address_space(1))) unsigned int*)g,
      (__attribute__((address_space(3))) unsigned int*)s, 16, 0, 0);
}

// ---------------- sparse expert GEMM (128x128 tile, BK=64, 4 waves) ----------------
// PASS 1: C = gathered(Xb) @ W1[e]^T-view, epilogue swish -> H (bf16)
// PASS 2: C = gathered(H) @ W2[e]^T-view, epilogue *= gate, atomicAdd -> out (fp32)
template <int PASS>
__launch_bounds__(256, 2)
__global__ void moe_gemm(const ushort* __restrict__ Abase,
                         const ushort* __restrict__ Wt,
                         const int* __restrict__ cnt,
                         const int* __restrict__ list,
                         const float* __restrict__ wa,
                         ushort* __restrict__ H,
                         float* __restrict__ out) {
  constexpr int K = (PASS == 1) ? DM : DFF;
  constexpr int NB = (PASS == 1) ? DFF : DM;
  const int e = blockIdx.z;
  const int n = cnt[e];
  const int tTile = blockIdx.y;
  if (tTile * 128 >= n) return;  // uniform early-exit, before any barrier
  const int nTile = blockIdx.x;

  __shared__ __attribute__((aligned(16))) char As[128 * 128];  // [row][64 bf16] = 128B rows
  __shared__ __attribute__((aligned(16))) char Bs[128 * 128];
  __shared__ int aL[128];
  __shared__ unsigned long long pL[128];

  const int tid = threadIdx.x;
  if (tid < 128) {
    int slot = tTile * 128 + tid;
    int sl = (slot < n) ? slot : (n - 1);
    int a = list[e * NTOK + sl];
    aL[tid] = (slot < n) ? a : -1;
    size_t row = (PASS == 1) ? (size_t)(a >> 1) : (size_t)a;
    pL[tid] = (unsigned long long)(Abase + row * K);  // byte address of A row
  }
  __syncthreads();

  const int wv = tid >> 6, lane = tid & 63;
  // per-lane staging source addrs (swizzle folded into SOURCE column; LDS dest linear)
  unsigned long long srcA[4], srcB[4];
  unsigned int dstOff[4];
  const char* WtE = (const char*)(Wt + (size_t)e * NB * K);
#pragma unroll
  for (int i = 0; i < 4; ++i) {
    int row = wv * 32 + i * 8 + (lane >> 3);                // LDS-local row 0..127
    int cb = ((lane & 7) * 16) ^ ((row & 7) << 4);          // pre-swizzled byte col
    srcA[i] = pL[row] + cb;
    srcB[i] = (unsigned long long)(WtE + ((size_t)(nTile * 128 + row) * K) * 2 + cb);
    dstOff[i] = row * 128 + (lane & 7) * 16;                // linear LDS slot
  }

  f32x4 acc[4][4];
#pragma unroll
  for (int m = 0; m < 4; ++m)
#pragma unroll
    for (int nn = 0; nn < 4; ++nn) acc[m][nn] = (f32x4){0.f, 0.f, 0.f, 0.f};

  const int r0 = (wv >> 1) * 64, c0 = (wv & 1) * 64;

  for (int kt = 0; kt < K / 64; ++kt) {
#pragma unroll
    for (int i = 0; i < 4; ++i) {
      gl_lds16((const void*)srcA[i], As + dstOff[i]);
      gl_lds16((const void*)srcB[i], Bs + dstOff[i]);
      srcA[i] += 128;
      srcB[i] += 128;
    }
    __syncthreads();  // compiler drains vmcnt(0) before s_barrier
#pragma unroll
    for (int kk = 0; kk < 2; ++kk) {
      bf16x8 af[4], bf[4];
#pragma unroll
      for (int m = 0; m < 4; ++m) {
        int row = r0 + m * 16 + (lane & 15);
        int kb = (kk * 32 + (lane >> 4) * 8) * 2;
        af[m] = *reinterpret_cast<const bf16x8*>(As + row * 128 + (kb ^ ((row & 7) << 4)));
      }
#pragma unroll
      for (int nn = 0; nn < 4; ++nn) {
        int row = c0 + nn * 16 + (lane & 15);
        int kb = (kk * 32 + (lane >> 4) * 8) * 2;
        bf[nn] = *reinterpret_cast<const bf16x8*>(Bs + row * 128 + (kb ^ ((row & 7) << 4)));
      }
#pragma unroll
      for (int m = 0; m < 4; ++m)
#pragma unroll
        for (int nn = 0; nn < 4; ++nn)
          acc[m][nn] = __builtin_amdgcn_mfma_f32_16x16x32_bf16(af[m], bf[nn], acc[m][nn], 0, 0, 0);
    }
    __syncthreads();
  }

  // epilogue — C/D layout: col = lane&15, row = (lane>>4)*4 + j  [m89-verified]
#pragma unroll
  for (int m = 0; m < 4; ++m) {
#pragma unroll
    for (int j = 0; j < 4; ++j) {
      int lr = r0 + m * 16 + (lane >> 4) * 4 + j;
      int a = aL[lr];
      if (a < 0) continue;
      if (PASS == 1) {
        ushort* hrow = H + (size_t)a * DFF + nTile * 128 + c0 + (lane & 15);
#pragma unroll
        for (int nn = 0; nn < 4; ++nn) {
          float v = acc[m][nn][j];
          float sw = v / (1.f + expf(-v));  // swish
          hrow[nn * 16] = f2bf(sw);
        }
      } else {
        float w = wa[a];
        int tok = a >> 1;
        float* orow = out + (size_t)tok * DM + nTile * 128 + c0 + (lane & 15);
#pragma unroll
        for (int nn = 0; nn < 4; ++nn)
          atomicAdd(&orow[nn * 16], w * acc[m][nn][j]);  // exactly 2 contributions: commutative-exact
      }
    }
  }
}

extern "C" void kernel_launch(void* const* d_in, const int* in_sizes, int n_in,
                              void* d_out, int out_size, void* d_ws, size_t ws_size,
                              hipStream_t stream) {
  const float* x = (const float*)d_in[0];
  const float* router = (const float*)d_in[1];
  const float* W1 = (const float*)d_in[2];
  const float* W2 = (const float*)d_in[3];
  float* out = (float*)d_out;
  char* ws = (char*)d_ws;

  size_t off = 0;
  ushort* Xb = (ushort*)(ws + off); off += (size_t)NTOK * DM * 2;          // 16 MB
  ushort* Wt1 = (ushort*)(ws + off); off += (size_t)NE * DM * DFF * 2;     // 64 MB
  ushort* Wt2 = (ushort*)(ws + off); off += (size_t)NE * DM * DFF * 2;     // 64 MB
  ushort* H   = (ushort*)(ws + off); off += (size_t)NTOK * 2 * DFF * 2;    // 128 MB
  int* cnt  = (int*)(ws + off); off += 256;
  int* list = (int*)(ws + off); off += (size_t)NE * NTOK * 4;
  float* wa = (float*)(ws + off); off += (size_t)NTOK * 2 * 4;

  hipMemsetAsync(out, 0, (size_t)NTOK * DM * sizeof(float), stream);
  hipMemsetAsync(cnt, 0, NE * sizeof(int), stream);

  cvt_x_kernel<<<NTOK * DM / 4 / 256, 256, 0, stream>>>(x, Xb);
  transpose_cvt<<<dim3(DFF / 64, DM / 64, NE), 256, 0, stream>>>(W1, Wt1, DM, DFF);
  transpose_cvt<<<dim3(DM / 64, DFF / 64, NE), 256, 0, stream>>>(W2, Wt2, DFF, DM);
  router_kernel<<<NTOK / 32, 256, 0, stream>>>(x, router, cnt, list, wa);

  moe_gemm<1><<<dim3(DFF / 128, NTOK / 128, NE), 256, 0, stream>>>(Xb, Wt1, cnt, list, wa, H, out);
  moe_gemm<2><<<dim3(DM / 128, NTOK / 128, NE), 256, 0, stream>>>(H, Wt2, cnt, list, wa, H, out);
}